// Round 13
// baseline (792.561 us; speedup 1.0000x reference)
//
#include <hip/hip_runtime.h>
#include <stdint.h>

// out[b,o,m] = sum_i in[b,i,m] * w[i,o,m]  (complex, fp32)
// B=32, Ci=Co=128, M=64*65=4160. One float2 per complex element.
//
// R13 = R12 (lane = mode, no LDS, no barriers, depth-2 register prefetch)
// with ONE change: NO XCD job swizzle. R12's per-XCD disjoint jid ranges
// put 64 different m-tiles in flight chip-wide -> A working set ~128MB +
// W stream thrashed L3 -> A re-fetched 6.6x (FETCH 1.44GB) and loaded
// latency blew up the pipeline. Plain mt-major order + round-robin
// dispatch keeps ~8 consecutive m-tiles in flight chip-wide (~16MB A),
// so A is HBM-read once and L2/L3-served 15x.
// Job = 32b x 8o x 64modes per block (8 waves, wave = 4b x 8o x 64m).
// W reads + O writes nontemporal (single-use streams, protect A in cache).

typedef float f2 __attribute__((ext_vector_type(2)));

#define CI 128
#define CO 128
#define MODES 4160
#define MT 64      // modes per tile  (4160/64 = 65 tiles)
#define OT 8       // o per block     (128/8  = 16 o-jobs)

// acc.lo += a.lo*w.lo - a.hi*w.hi ; acc.hi += a.lo*w.hi + a.hi*w.lo
#define CFMA(acc, av, wv)                                                      \
  asm("v_pk_fma_f32 %0, %1, %2, %0 op_sel:[0,0,0] op_sel_hi:[0,1,1]"           \
      : "+v"(acc) : "v"(av), "v"(wv));                                         \
  asm("v_pk_fma_f32 %0, %1, %2, %0 op_sel:[1,1,0] op_sel_hi:[1,0,1] "          \
      "neg_lo:[1,0,0]"                                                         \
      : "+v"(acc) : "v"(av), "v"(wv));

// W (HBM, long latency) issued FIRST, then A (L1/L2/L3, short latency).
#define LOADK(aa, ww, kk)                                                      \
  {                                                                            \
    _Pragma("unroll") for (int q = 0; q < 8; ++q)                              \
        ww[q] = __builtin_nontemporal_load(&Wb[((size_t)(kk) * CO + q) * MODES]); \
    _Pragma("unroll") for (int r = 0; r < 4; ++r)                              \
        aa[r] = Ab[((size_t)r * CI + (kk)) * MODES];                           \
  }

#define COMP(aa, ww)                                                           \
  _Pragma("unroll") for (int r = 0; r < 4; ++r)                                \
  _Pragma("unroll") for (int q = 0; q < 8; ++q) { CFMA(acc[r][q], aa[r], ww[q]); }

__global__ __launch_bounds__(512, 4)
void cmul2d_kernel(const f2* __restrict__ Ig,
                   const f2* __restrict__ Wl,
                   f2* __restrict__ Og) {
    const int t   = threadIdx.x;
    const int bid = blockIdx.x;

    // plain mt-major map: consecutive bids = the 16 o-jobs of one m-tile,
    // round-robin-dispatched across XCDs -> chip-wide m-window stays small.
    const int mt  = bid >> 4;            // 0..64
    const int ot  = bid & 15;            // 0..15
    const int m0  = mt * MT;
    const int o0  = ot * OT;

    const int wave = t >> 6;             // 0..7 -> b-quad
    const int lane = t & 63;             // = mode within tile
    const int b0   = wave * 4;

    const f2* Ab = Ig + ((size_t)b0 * CI) * MODES + m0 + lane;
    const f2* Wb = Wl + (size_t)o0 * MODES + m0 + lane;

    f2 acc[4][8];
#pragma unroll
    for (int r = 0; r < 4; ++r)
#pragma unroll
        for (int q = 0; q < 8; ++q) acc[r][q] = (f2)(0.0f);

    f2 a0[4], w0[8], a1[4], w1[8];
    LOADK(a0, w0, 0);                    // k = 0

#pragma unroll 1
    for (int k = 0; k < CI; k += 2) {
        LOADK(a1, w1, k + 1);            // issue k+1 (12 loads in flight)
        COMP(a0, w0);                    // compute k
        if (k + 2 < CI) LOADK(a0, w0, k + 2);
        COMP(a1, w1);                    // compute k+1
    }

    // stores: 64 lanes = 64 consecutive modes -> 512B lines, single-use
#pragma unroll
    for (int r = 0; r < 4; ++r) {
        const int b = b0 + r;
#pragma unroll
        for (int q = 0; q < 8; ++q) {
            __builtin_nontemporal_store(
                acc[r][q],
                &Og[((size_t)b * CO + o0 + q) * MODES + m0 + lane]);
        }
    }
}

extern "C" void kernel_launch(void* const* d_in, const int* in_sizes, int n_in,
                              void* d_out, int out_size, void* d_ws, size_t ws_size,
                              hipStream_t stream) {
    const f2* I = (const f2*)d_in[0];
    const f2* W = (const f2*)d_in[1];
    f2* O = (f2*)d_out;
    dim3 grid(1040);   // 65 m-tiles x 16 o-jobs, mt-major
    dim3 block(512);   // 8 waves x (4b x 8o x 64m)
    cmul2d_kernel<<<grid, block, 0, stream>>>(I, W, O);
}